// Round 1
// baseline (213.095 us; speedup 1.0000x reference)
//
#include <hip/hip_runtime.h>
#include <hip/hip_bf16.h>
#include <cstddef>

#define T_TOK 1024
#define D_DIM 1024
#define H_DIM 512
#define E_EXP 8
#define EH    (E_EXP * H_DIM)   // 4096

typedef __attribute__((ext_vector_type(4))) float  float4_t;
typedef __attribute__((ext_vector_type(4))) short  short4_t;
typedef __attribute__((ext_vector_type(8))) short  short8_t;

__device__ __forceinline__ short f2bf(float f) {
    union { float f; unsigned u; } v; v.f = f;
    unsigned u = v.u;
    u += 0x7FFFu + ((u >> 16) & 1u);   // RNE; inputs are finite
    return (short)(u >> 16);
}

// ---------------- router: logits -> softmax -> top2 -> scale[T][E] ----------
__global__ __launch_bounds__(64) void router_kernel(
    const float* __restrict__ x, const float* __restrict__ gw,
    float* __restrict__ scale) {
  const int t = blockIdx.x;
  const int lane = threadIdx.x;
  const float* xr = x + (size_t)t * D_DIM;
  float acc[E_EXP];
  #pragma unroll
  for (int e = 0; e < E_EXP; ++e) acc[e] = 0.f;
  for (int d = lane; d < D_DIM; d += 64) {
    float xv = xr[d];
    #pragma unroll
    for (int e = 0; e < E_EXP; ++e) acc[e] += xv * gw[d * E_EXP + e];
  }
  #pragma unroll
  for (int off = 32; off >= 1; off >>= 1) {
    #pragma unroll
    for (int e = 0; e < E_EXP; ++e) acc[e] += __shfl_down(acc[e], off, 64);
  }
  if (lane == 0) {
    float m = acc[0];
    #pragma unroll
    for (int e = 1; e < E_EXP; ++e) m = fmaxf(m, acc[e]);
    float p[E_EXP]; float s = 0.f;
    #pragma unroll
    for (int e = 0; e < E_EXP; ++e) { p[e] = __expf(acc[e] - m); s += p[e]; }
    float inv = 1.f / s;
    #pragma unroll
    for (int e = 0; e < E_EXP; ++e) p[e] *= inv;
    int i1 = 0;
    #pragma unroll
    for (int e = 1; e < E_EXP; ++e) if (p[e] > p[i1]) i1 = e;  // strict > == jax low-index tiebreak
    int i2 = -1;
    #pragma unroll
    for (int e = 0; e < E_EXP; ++e) {
      if (e == i1) continue;
      if (i2 < 0 || p[e] > p[i2]) i2 = e;
    }
    #pragma unroll
    for (int e = 0; e < E_EXP; ++e)
      scale[t * E_EXP + e] = (e == i1 || e == i2) ? p[e] : 0.f;
  }
}

// ---------------- GEMM1: h[t][e*512+n] = silu((s*x)@w1e) * ((s*x)@w3e) ------
#define LDA1 36   // shorts per LDS row (32 data + 4 pad) -> 72B rows, b64-aligned

__global__ __launch_bounds__(256, 1) void gemm1_kernel(
    const float* __restrict__ x, const float* __restrict__ w1,
    const float* __restrict__ w3, const float* __restrict__ scale,
    short* __restrict__ h) {
  __shared__ short As [128 * LDA1];  // A[m][k], scaled-x bf16
  __shared__ short B1s[128 * LDA1];  // B1^T [n][k]
  __shared__ short B3s[128 * LDA1];  // B3^T [n][k]

  const int nt = blockIdx.x;           // 0..3  (H/128)
  const int mt = blockIdx.y;           // 0..7  (T/128)
  const int e  = blockIdx.z;           // 0..7
  const int n0 = nt * 128;
  const int m0 = mt * 128;
  const int tid  = threadIdx.x;
  const int lane = tid & 63;
  const int wid  = tid >> 6;
  const int wr = wid >> 1, wc = wid & 1;   // 2x2 wave grid, each 64x64
  const int q = lane >> 4, ln = lane & 15;

  const float* w1e = w1 + (size_t)e * D_DIM * H_DIM;
  const float* w3e = w3 + (size_t)e * D_DIM * H_DIM;

  // A staging mapping: 128 rows x 8 k-quads; 256 thr -> 4 row-iters
  const int a_row = tid >> 3;   // 0..31
  const int a_k4  = tid & 7;    // 0..7
  float sc[4];
  #pragma unroll
  for (int rr = 0; rr < 4; ++rr)
    sc[rr] = scale[(m0 + rr * 32 + a_row) * E_EXP + e];

  // B staging mapping: (k-group, n-quad)
  const int b_kg = tid >> 5;    // 0..7   (k 4-groups)
  const int b_n4 = tid & 31;    // 0..31  (n quads)

  float4_t acc1[4][4], acc3[4][4];
  #pragma unroll
  for (int i = 0; i < 4; ++i)
    #pragma unroll
    for (int j = 0; j < 4; ++j) {
      acc1[i][j] = (float4_t){0.f, 0.f, 0.f, 0.f};
      acc3[i][j] = (float4_t){0.f, 0.f, 0.f, 0.f};
    }

  for (int k0 = 0; k0 < D_DIM; k0 += 32) {
    // ---- stage A: 128x32 scaled x -> bf16
    #pragma unroll
    for (int rr = 0; rr < 4; ++rr) {
      int r = rr * 32 + a_row;
      float4_t v = *(const float4_t*)(x + (size_t)(m0 + r) * D_DIM + k0 + a_k4 * 4);
      float s = sc[rr];
      short4_t b;
      b[0] = f2bf(v[0] * s); b[1] = f2bf(v[1] * s);
      b[2] = f2bf(v[2] * s); b[3] = f2bf(v[3] * s);
      *(short4_t*)(&As[r * LDA1 + a_k4 * 4]) = b;
    }
    // ---- stage B1,B3: 32x128 -> transposed [n][k] bf16
    {
      float4_t v1[4], v3[4];
      #pragma unroll
      for (int j = 0; j < 4; ++j) {
        int krow = k0 + b_kg * 4 + j;
        v1[j] = *(const float4_t*)(w1e + (size_t)krow * H_DIM + n0 + b_n4 * 4);
        v3[j] = *(const float4_t*)(w3e + (size_t)krow * H_DIM + n0 + b_n4 * 4);
      }
      #pragma unroll
      for (int i = 0; i < 4; ++i) {
        short4_t b1, b3;
        b1[0] = f2bf(v1[0][i]); b1[1] = f2bf(v1[1][i]);
        b1[2] = f2bf(v1[2][i]); b1[3] = f2bf(v1[3][i]);
        b3[0] = f2bf(v3[0][i]); b3[1] = f2bf(v3[1][i]);
        b3[2] = f2bf(v3[2][i]); b3[3] = f2bf(v3[3][i]);
        int n = b_n4 * 4 + i;
        *(short4_t*)(&B1s[n * LDA1 + b_kg * 4]) = b1;
        *(short4_t*)(&B3s[n * LDA1 + b_kg * 4]) = b3;
      }
    }
    __syncthreads();

    // ---- fragments + MFMA
    short8_t af[4], b1f[4], b3f[4];
    #pragma unroll
    for (int i = 0; i < 4; ++i) {
      int m_l = wr * 64 + i * 16 + ln;
      short4_t lo = *(const short4_t*)(&As[m_l * LDA1 + q * 8]);
      short4_t hi = *(const short4_t*)(&As[m_l * LDA1 + q * 8 + 4]);
      af[i] = __builtin_shufflevector(lo, hi, 0, 1, 2, 3, 4, 5, 6, 7);
    }
    #pragma unroll
    for (int j = 0; j < 4; ++j) {
      int n_l = wc * 64 + j * 16 + ln;
      short4_t lo1 = *(const short4_t*)(&B1s[n_l * LDA1 + q * 8]);
      short4_t hi1 = *(const short4_t*)(&B1s[n_l * LDA1 + q * 8 + 4]);
      b1f[j] = __builtin_shufflevector(lo1, hi1, 0, 1, 2, 3, 4, 5, 6, 7);
      short4_t lo3 = *(const short4_t*)(&B3s[n_l * LDA1 + q * 8]);
      short4_t hi3 = *(const short4_t*)(&B3s[n_l * LDA1 + q * 8 + 4]);
      b3f[j] = __builtin_shufflevector(lo3, hi3, 0, 1, 2, 3, 4, 5, 6, 7);
    }
    #pragma unroll
    for (int i = 0; i < 4; ++i)
      #pragma unroll
      for (int j = 0; j < 4; ++j) {
        acc1[i][j] = __builtin_amdgcn_mfma_f32_16x16x32_bf16(af[i], b1f[j], acc1[i][j], 0, 0, 0);
        acc3[i][j] = __builtin_amdgcn_mfma_f32_16x16x32_bf16(af[i], b3f[j], acc3[i][j], 0, 0, 0);
      }
    __syncthreads();
  }

  // ---- epilogue: silu(c1)*c3 -> h bf16, layout [t][e*H + n]
  #pragma unroll
  for (int i = 0; i < 4; ++i) {
    int r_base = m0 + wr * 64 + i * 16 + q * 4;
    #pragma unroll
    for (int j = 0; j < 4; ++j) {
      int hcol = n0 + wc * 64 + j * 16 + ln;
      #pragma unroll
      for (int rr = 0; rr < 4; ++rr) {
        float c1 = acc1[i][j][rr];
        float c3 = acc3[i][j][rr];
        float sig = 1.f / (1.f + __expf(-c1));
        float hv = c1 * sig * c3;
        h[(size_t)(r_base + rr) * EH + e * H_DIM + hcol] = f2bf(hv);
      }
    }
  }
}

// ---------------- GEMM2: out[1024][1024] = h[1024][4096] @ w2cat[4096][1024]
#define LDA2 72   // A rows: 64 data + 8 pad shorts (144B, 16B-aligned)
#define LDB2 68   // B rows: 64 data + 4 pad shorts (136B, 8B-aligned)

__global__ __launch_bounds__(256, 1) void gemm2_kernel(
    const short* __restrict__ h, const float* __restrict__ w2,
    float* __restrict__ out) {
  __shared__ short As[64 * LDA2];   // [m][k]
  __shared__ short Bs[64 * LDB2];   // [n][k] (transposed w2)
  const int nt = blockIdx.x, mt = blockIdx.y;
  const int n0 = nt * 64, m0 = mt * 64;
  const int tid  = threadIdx.x;
  const int lane = tid & 63;
  const int wid  = tid >> 6;
  const int wr = wid >> 1, wc = wid & 1;   // 2x2 waves, each 32x32
  const int q = lane >> 4, ln = lane & 15;

  const int b_kq = tid >> 4;   // 0..15 (k 4-groups)
  const int b_n4 = tid & 15;   // 0..15 (n quads)

  float4_t acc[2][2];
  #pragma unroll
  for (int i = 0; i < 2; ++i)
    #pragma unroll
    for (int j = 0; j < 2; ++j) acc[i][j] = (float4_t){0.f, 0.f, 0.f, 0.f};

  for (int k0 = 0; k0 < EH; k0 += 64) {
    // ---- stage A from h (already bf16): 64x64, raw 16B copies
    #pragma unroll
    for (int it = 0; it < 2; ++it) {
      int idx = tid + it * 256;
      int m = idx >> 3, ko = idx & 7;
      float4_t v = *(const float4_t*)(h + (size_t)(m0 + m) * EH + k0 + ko * 8);
      *(float4_t*)(&As[m * LDA2 + ko * 8]) = v;
    }
    // ---- stage B from w2: 64k x 64n -> transposed [n][k] bf16
    {
      float4_t v[4];
      #pragma unroll
      for (int j = 0; j < 4; ++j)
        v[j] = *(const float4_t*)(w2 + (size_t)(k0 + b_kq * 4 + j) * D_DIM + n0 + b_n4 * 4);
      #pragma unroll
      for (int i = 0; i < 4; ++i) {
        short4_t b;
        b[0] = f2bf(v[0][i]); b[1] = f2bf(v[1][i]);
        b[2] = f2bf(v[2][i]); b[3] = f2bf(v[3][i]);
        *(short4_t*)(&Bs[(b_n4 * 4 + i) * LDB2 + b_kq * 4]) = b;
      }
    }
    __syncthreads();

    #pragma unroll
    for (int kk = 0; kk < 2; ++kk) {
      short8_t af[2], bf[2];
      #pragma unroll
      for (int i = 0; i < 2; ++i) {
        int m_l = wr * 32 + i * 16 + ln;
        const short* p = &As[m_l * LDA2 + kk * 32 + q * 8];
        short4_t lo = *(const short4_t*)p;
        short4_t hi = *(const short4_t*)(p + 4);
        af[i] = __builtin_shufflevector(lo, hi, 0, 1, 2, 3, 4, 5, 6, 7);
      }
      #pragma unroll
      for (int j = 0; j < 2; ++j) {
        int n_l = wc * 32 + j * 16 + ln;
        const short* p = &Bs[n_l * LDB2 + kk * 32 + q * 8];
        short4_t lo = *(const short4_t*)p;
        short4_t hi = *(const short4_t*)(p + 4);
        bf[j] = __builtin_shufflevector(lo, hi, 0, 1, 2, 3, 4, 5, 6, 7);
      }
      #pragma unroll
      for (int i = 0; i < 2; ++i)
        #pragma unroll
        for (int j = 0; j < 2; ++j)
          acc[i][j] = __builtin_amdgcn_mfma_f32_16x16x32_bf16(af[i], bf[j], acc[i][j], 0, 0, 0);
    }
    __syncthreads();
  }

  // ---- epilogue: fp32 store, full coverage (no init needed)
  #pragma unroll
  for (int i = 0; i < 2; ++i) {
    int r_base = m0 + wr * 32 + i * 16 + q * 4;
    #pragma unroll
    for (int j = 0; j < 2; ++j) {
      int c = n0 + wc * 32 + j * 16 + ln;
      #pragma unroll
      for (int rr = 0; rr < 4; ++rr)
        out[(size_t)(r_base + rr) * D_DIM + c] = acc[i][j][rr];
    }
  }
}

extern "C" void kernel_launch(void* const* d_in, const int* in_sizes, int n_in,
                              void* d_out, int out_size, void* d_ws, size_t ws_size,
                              hipStream_t stream) {
  const float* x  = (const float*)d_in[0];   // [2,512,1024]
  const float* gw = (const float*)d_in[1];   // [1024,8]
  const float* w1 = (const float*)d_in[2];   // [8,1024,512] gate
  const float* w2 = (const float*)d_in[3];   // [8,512,1024] down
  const float* w3 = (const float*)d_in[4];   // [8,1024,512] up
  float* out = (float*)d_out;

  float* scale = (float*)d_ws;                          // 1024*8 fp32 = 32KB
  short* h     = (short*)((char*)d_ws + 65536);         // 1024*4096 bf16 = 8MB

  router_kernel<<<dim3(T_TOK), dim3(64), 0, stream>>>(x, gw, scale);

  dim3 g1(H_DIM / 128, T_TOK / 128, E_EXP);             // 4 x 8 x 8 = 256 blocks
  gemm1_kernel<<<g1, dim3(256), 0, stream>>>(x, w1, w3, scale, h);

  dim3 g2(D_DIM / 64, T_TOK / 64);                      // 16 x 16 = 256 blocks
  gemm2_kernel<<<g2, dim3(256), 0, stream>>>(h, w2, out);
}

// Round 2
// 152.284 us; speedup vs baseline: 1.3993x; 1.3993x over previous
//
#include <hip/hip_runtime.h>
#include <hip/hip_bf16.h>
#include <cstddef>

#define T_TOK 1024
#define D_DIM 1024
#define H_DIM 512
#define E_EXP 8
#define P_CAP 2560          // max padded pairs: 2048 + 8*63 = 2552 -> 2560
#define MAX_MT (P_CAP / 64) // 40 m-tile slots
#define LDA 72              // shorts per LDS row: 64 data + 8 pad (144B, 16B-aligned)

typedef __attribute__((ext_vector_type(4))) float    float4_t;
typedef __attribute__((ext_vector_type(4))) short    short4_t;
typedef __attribute__((ext_vector_type(8))) short    short8_t;
typedef __attribute__((ext_vector_type(4))) unsigned uint4_t;
typedef __attribute__((ext_vector_type(2))) unsigned uint2_t;

__device__ __forceinline__ short f2bf(float f) {
  union { float f; unsigned u; } v; v.f = f;
  unsigned u = v.u;
  u += 0x7FFFu + ((u >> 16) & 1u);
  return (short)(u >> 16);
}

// packed fp32x2 -> bf16x2 (v_cvt_pk_bf16_f32 on gfx950)
__device__ __forceinline__ unsigned pkbf(float a, float b) {
  union { __hip_bfloat162 h; unsigned u; } v;
  v.h = __float22bfloat162_rn(make_float2(a, b));
  return v.u;
}

// ---------------- router: logits -> softmax -> top2 (idx + score) ----------
__global__ __launch_bounds__(256) void router_kernel(
    const float* __restrict__ x, const float* __restrict__ gw,
    int* __restrict__ idx2, float* __restrict__ scale2) {
  const int wid  = threadIdx.x >> 6;
  const int lane = threadIdx.x & 63;
  const int t = blockIdx.x * 4 + wid;
  const float* xr = x + (size_t)t * D_DIM;
  float acc[E_EXP];
  #pragma unroll
  for (int e = 0; e < E_EXP; ++e) acc[e] = 0.f;
  for (int d = lane; d < D_DIM; d += 64) {
    float xv = xr[d];
    float4_t g0 = *(const float4_t*)(gw + d * E_EXP);
    float4_t g1 = *(const float4_t*)(gw + d * E_EXP + 4);
    acc[0] += xv * g0[0]; acc[1] += xv * g0[1];
    acc[2] += xv * g0[2]; acc[3] += xv * g0[3];
    acc[4] += xv * g1[0]; acc[5] += xv * g1[1];
    acc[6] += xv * g1[2]; acc[7] += xv * g1[3];
  }
  #pragma unroll
  for (int off = 32; off >= 1; off >>= 1) {
    #pragma unroll
    for (int e = 0; e < E_EXP; ++e) acc[e] += __shfl_down(acc[e], off, 64);
  }
  if (lane == 0) {
    float m = acc[0];
    #pragma unroll
    for (int e = 1; e < E_EXP; ++e) m = fmaxf(m, acc[e]);
    float p[E_EXP]; float s = 0.f;
    #pragma unroll
    for (int e = 0; e < E_EXP; ++e) { p[e] = __expf(acc[e] - m); s += p[e]; }
    float inv = 1.f / s;
    #pragma unroll
    for (int e = 0; e < E_EXP; ++e) p[e] *= inv;
    int i1 = 0;
    #pragma unroll
    for (int e = 1; e < E_EXP; ++e) if (p[e] > p[i1]) i1 = e;  // jax low-index tiebreak
    int i2 = (i1 == 0) ? 1 : 0;
    #pragma unroll
    for (int e = 0; e < E_EXP; ++e) {
      if (e == i1 || e == i2) continue;
      if (p[e] > p[i2]) i2 = e;
    }
    idx2[2 * t]     = i1;  scale2[2 * t]     = p[i1];
    idx2[2 * t + 1] = i2;  scale2[2 * t + 1] = p[i2];
  }
}

// ---- scan/assign: histogram -> aligned bases -> tile table -> pair lists ---
__global__ __launch_bounds__(256) void scan_kernel(
    const int* __restrict__ idx2, const float* __restrict__ scale2,
    int* __restrict__ pair_tok, float* __restrict__ pair_scale,
    int* __restrict__ pairpos, int* __restrict__ meta) {
  __shared__ int cnt[E_EXP], base[E_EXP], cur[E_EXP];
  const int tid = threadIdx.x;
  if (tid < E_EXP) { cnt[tid] = 0; cur[tid] = 0; }
  for (int p = tid; p < P_CAP; p += 256) { pair_tok[p] = 0; pair_scale[p] = 0.f; }
  __syncthreads();
  for (int t = tid; t < T_TOK; t += 256) {
    atomicAdd(&cnt[idx2[2 * t]], 1);
    atomicAdd(&cnt[idx2[2 * t + 1]], 1);
  }
  __syncthreads();
  if (tid == 0) {
    int b = 0, g = 0;
    for (int e = 0; e < E_EXP; ++e) {
      base[e] = b;
      int al = (cnt[e] + 63) & ~63;
      for (int j = 0; j < al; j += 64) { meta[1 + g] = e; meta[41 + g] = b + j; ++g; }
      b += al;
    }
    meta[0] = g;  // n_mtiles
  }
  __syncthreads();
  for (int t = tid; t < T_TOK; t += 256) {
    #pragma unroll
    for (int s = 0; s < 2; ++s) {
      int e = idx2[2 * t + s];
      int p = base[e] + atomicAdd(&cur[e], 1);
      pair_tok[p] = t;
      pair_scale[p] = scale2[2 * t + s];
      pairpos[2 * t + s] = p;
    }
  }
}

// ------- gemm1 (compacted): h[p][H] = silu((s*x_tok)@w1e) * ((s*x_tok)@w3e) -
__global__ __launch_bounds__(256, 2) void gemm1_kernel(
    const float* __restrict__ x, const float* __restrict__ w1,
    const float* __restrict__ w3,
    const int* __restrict__ pair_tok, const float* __restrict__ pair_scale,
    const int* __restrict__ meta, short* __restrict__ h) {
  __shared__ short As[64 * LDA], B1s[64 * LDA], B3s[64 * LDA];
  const int mt = blockIdx.y;
  if (mt >= meta[0]) return;
  const int e    = meta[1 + mt];
  const int row0 = meta[41 + mt];
  const int n0   = blockIdx.x * 64;
  const int tid = threadIdx.x, lane = tid & 63, wid = tid >> 6;
  const int wr = wid >> 1, wc = wid & 1;
  const int q = lane >> 4, ln = lane & 15;
  const float* w1e = w1 + (size_t)e * D_DIM * H_DIM;
  const float* w3e = w3 + (size_t)e * D_DIM * H_DIM;

  // A staging: thread owns one 16-float k-segment of one row
  const int ar = tid >> 2, ak = tid & 3;
  const int   tok = pair_tok[row0 + ar];
  const float sc  = pair_scale[row0 + ar];
  const float* xrow = x + (size_t)tok * D_DIM + ak * 16;

  // B staging: (k-quad, n-quad)
  const int bk = tid >> 4, bn = tid & 15;

  float4_t acc1[2][2], acc3[2][2];
  #pragma unroll
  for (int i = 0; i < 2; ++i)
    #pragma unroll
    for (int j = 0; j < 2; ++j) {
      acc1[i][j] = (float4_t){0.f, 0.f, 0.f, 0.f};
      acc3[i][j] = (float4_t){0.f, 0.f, 0.f, 0.f};
    }

  for (int k0 = 0; k0 < D_DIM; k0 += 64) {
    // ---- A: gather row, scale, convert, store [m][k]
    {
      float4_t v0 = *(const float4_t*)(xrow + k0);
      float4_t v1 = *(const float4_t*)(xrow + k0 + 4);
      float4_t v2 = *(const float4_t*)(xrow + k0 + 8);
      float4_t v3 = *(const float4_t*)(xrow + k0 + 12);
      uint4_t u0 = {pkbf(v0[0] * sc, v0[1] * sc), pkbf(v0[2] * sc, v0[3] * sc),
                    pkbf(v1[0] * sc, v1[1] * sc), pkbf(v1[2] * sc, v1[3] * sc)};
      uint4_t u1 = {pkbf(v2[0] * sc, v2[1] * sc), pkbf(v2[2] * sc, v2[3] * sc),
                    pkbf(v3[0] * sc, v3[1] * sc), pkbf(v3[2] * sc, v3[3] * sc)};
      *(uint4_t*)&As[ar * LDA + ak * 16]     = u0;
      *(uint4_t*)&As[ar * LDA + ak * 16 + 8] = u1;
    }
    // ---- B1/B3: 64k x 64n fp32 -> transposed [n][k] bf16
    {
      const float* p1 = w1e + (size_t)(k0 + bk * 4) * H_DIM + n0 + bn * 4;
      const float* p3 = w3e + (size_t)(k0 + bk * 4) * H_DIM + n0 + bn * 4;
      float4_t a0 = *(const float4_t*)(p1);
      float4_t a1 = *(const float4_t*)(p1 + H_DIM);
      float4_t a2 = *(const float4_t*)(p1 + 2 * H_DIM);
      float4_t a3 = *(const float4_t*)(p1 + 3 * H_DIM);
      float4_t c0 = *(const float4_t*)(p3);
      float4_t c1 = *(const float4_t*)(p3 + H_DIM);
      float4_t c2 = *(const float4_t*)(p3 + 2 * H_DIM);
      float4_t c3 = *(const float4_t*)(p3 + 3 * H_DIM);
      #pragma unroll
      for (int i = 0; i < 4; ++i) {
        uint2_t u1v = {pkbf(a0[i], a1[i]), pkbf(a2[i], a3[i])};
        uint2_t u3v = {pkbf(c0[i], c1[i]), pkbf(c2[i], c3[i])};
        *(uint2_t*)&B1s[(bn * 4 + i) * LDA + bk * 4] = u1v;
        *(uint2_t*)&B3s[(bn * 4 + i) * LDA + bk * 4] = u3v;
      }
    }
    __syncthreads();

    short8_t af[2][2], b1f[2][2], b3f[2][2];
    #pragma unroll
    for (int i = 0; i < 2; ++i)
      #pragma unroll
      for (int kk = 0; kk < 2; ++kk)
        af[i][kk] = *(const short8_t*)&As[(wr * 32 + i * 16 + ln) * LDA + kk * 32 + q * 8];
    #pragma unroll
    for (int j = 0; j < 2; ++j)
      #pragma unroll
      for (int kk = 0; kk < 2; ++kk) {
        b1f[j][kk] = *(const short8_t*)&B1s[(wc * 32 + j * 16 + ln) * LDA + kk * 32 + q * 8];
        b3f[j][kk] = *(const short8_t*)&B3s[(wc * 32 + j * 16 + ln) * LDA + kk * 32 + q * 8];
      }
    #pragma unroll
    for (int i = 0; i < 2; ++i)
      #pragma unroll
      for (int j = 0; j < 2; ++j)
        #pragma unroll
        for (int kk = 0; kk < 2; ++kk) {
          acc1[i][j] = __builtin_amdgcn_mfma_f32_16x16x32_bf16(af[i][kk], b1f[j][kk], acc1[i][j], 0, 0, 0);
          acc3[i][j] = __builtin_amdgcn_mfma_f32_16x16x32_bf16(af[i][kk], b3f[j][kk], acc3[i][j], 0, 0, 0);
        }
    __syncthreads();
  }

  // ---- epilogue: silu(c1)*c3 -> h[pair][H]
  #pragma unroll
  for (int i = 0; i < 2; ++i) {
    int r_base = row0 + wr * 32 + i * 16 + q * 4;
    #pragma unroll
    for (int j = 0; j < 2; ++j) {
      int col = n0 + wc * 32 + j * 16 + ln;
      #pragma unroll
      for (int rr = 0; rr < 4; ++rr) {
        float c1 = acc1[i][j][rr];
        float c3 = acc3[i][j][rr];
        float sig = 1.f / (1.f + __expf(-c1));
        h[(size_t)(r_base + rr) * H_DIM + col] = f2bf(c1 * sig * c3);
      }
    }
  }
}

// ------- gemm2 (compacted): y[p][D] = h[p][H] @ w2[e]  (K = 512 only) -------
__global__ __launch_bounds__(256, 2) void gemm2_kernel(
    const short* __restrict__ h, const float* __restrict__ w2,
    const int* __restrict__ meta, float* __restrict__ y) {
  __shared__ short As[64 * LDA], Bs[64 * LDA];
  const int mt = blockIdx.y;
  if (mt >= meta[0]) return;
  const int e    = meta[1 + mt];
  const int row0 = meta[41 + mt];
  const int n0   = blockIdx.x * 64;
  const int tid = threadIdx.x, lane = tid & 63, wid = tid >> 6;
  const int wr = wid >> 1, wc = wid & 1;
  const int q = lane >> 4, ln = lane & 15;
  const float* w2e = w2 + (size_t)e * H_DIM * D_DIM;

  const int ar = tid >> 2, ak = tid & 3;
  const short* hrow = h + (size_t)(row0 + ar) * H_DIM + ak * 16;
  const int bk = tid >> 4, bn = tid & 15;

  float4_t acc[2][2];
  #pragma unroll
  for (int i = 0; i < 2; ++i)
    #pragma unroll
    for (int j = 0; j < 2; ++j) acc[i][j] = (float4_t){0.f, 0.f, 0.f, 0.f};

  for (int k0 = 0; k0 < H_DIM; k0 += 64) {
    // A: already bf16, straight 16B copies
    {
      uint4_t u0 = *(const uint4_t*)(hrow + k0);
      uint4_t u1 = *(const uint4_t*)(hrow + k0 + 8);
      *(uint4_t*)&As[ar * LDA + ak * 16]     = u0;
      *(uint4_t*)&As[ar * LDA + ak * 16 + 8] = u1;
    }
    // B: w2e rows k (H-dim) x cols n (D-dim) -> transposed [n][k] bf16
    {
      const float* pb = w2e + (size_t)(k0 + bk * 4) * D_DIM + n0 + bn * 4;
      float4_t a0 = *(const float4_t*)(pb);
      float4_t a1 = *(const float4_t*)(pb + D_DIM);
      float4_t a2 = *(const float4_t*)(pb + 2 * D_DIM);
      float4_t a3 = *(const float4_t*)(pb + 3 * D_DIM);
      #pragma unroll
      for (int i = 0; i < 4; ++i) {
        uint2_t u = {pkbf(a0[i], a1[i]), pkbf(a2[i], a3[i])};
        *(uint2_t*)&Bs[(bn * 4 + i) * LDA + bk * 4] = u;
      }
    }
    __syncthreads();

    short8_t af[2][2], bf[2][2];
    #pragma unroll
    for (int i = 0; i < 2; ++i)
      #pragma unroll
      for (int kk = 0; kk < 2; ++kk)
        af[i][kk] = *(const short8_t*)&As[(wr * 32 + i * 16 + ln) * LDA + kk * 32 + q * 8];
    #pragma unroll
    for (int j = 0; j < 2; ++j)
      #pragma unroll
      for (int kk = 0; kk < 2; ++kk)
        bf[j][kk] = *(const short8_t*)&Bs[(wc * 32 + j * 16 + ln) * LDA + kk * 32 + q * 8];
    #pragma unroll
    for (int i = 0; i < 2; ++i)
      #pragma unroll
      for (int j = 0; j < 2; ++j)
        #pragma unroll
        for (int kk = 0; kk < 2; ++kk)
          acc[i][j] = __builtin_amdgcn_mfma_f32_16x16x32_bf16(af[i][kk], bf[j][kk], acc[i][j], 0, 0, 0);
    __syncthreads();
  }

  #pragma unroll
  for (int i = 0; i < 2; ++i) {
    int r_base = row0 + wr * 32 + i * 16 + q * 4;
    #pragma unroll
    for (int j = 0; j < 2; ++j) {
      int col = n0 + wc * 32 + j * 16 + ln;
      #pragma unroll
      for (int rr = 0; rr < 4; ++rr)
        y[(size_t)(r_base + rr) * D_DIM + col] = acc[i][j][rr];
    }
  }
}

// ---------------- combine: out[t] = y[pos(t,0)] + y[pos(t,1)] ---------------
__global__ __launch_bounds__(256) void combine_kernel(
    const float* __restrict__ y, const int* __restrict__ pairpos,
    float* __restrict__ out) {
  const int wid  = threadIdx.x >> 6;
  const int lane = threadIdx.x & 63;
  const int t = blockIdx.x * 4 + wid;
  const int p0 = pairpos[2 * t], p1 = pairpos[2 * t + 1];
  const float4_t* y0 = (const float4_t*)(y + (size_t)p0 * D_DIM);
  const float4_t* y1 = (const float4_t*)(y + (size_t)p1 * D_DIM);
  float4_t* o = (float4_t*)(out + (size_t)t * D_DIM);
  #pragma unroll
  for (int c = lane; c < D_DIM / 4; c += 64) o[c] = y0[c] + y1[c];
}

extern "C" void kernel_launch(void* const* d_in, const int* in_sizes, int n_in,
                              void* d_out, int out_size, void* d_ws, size_t ws_size,
                              hipStream_t stream) {
  const float* x  = (const float*)d_in[0];   // [2,512,1024]
  const float* gw = (const float*)d_in[1];   // [1024,8]
  const float* w1 = (const float*)d_in[2];   // [8,1024,512] gate
  const float* w2 = (const float*)d_in[3];   // [8,512,1024] down
  const float* w3 = (const float*)d_in[4];   // [8,1024,512] up
  float* out = (float*)d_out;

  char* ws = (char*)d_ws;
  int*   idx2    = (int*)  (ws);              // 8KB
  float* scale2  = (float*)(ws + 8192);       // 8KB
  int*   pairpos = (int*)  (ws + 16384);      // 8KB
  int*   ptok    = (int*)  (ws + 24576);      // 10KB (slot 16KB)
  float* pscale  = (float*)(ws + 40960);      // 10KB (slot 16KB)
  int*   meta    = (int*)  (ws + 57344);      // 512B
  short* h       = (short*)(ws + 65536);                          // 2.62MB
  float* y       = (float*)(ws + 65536 + (size_t)P_CAP * H_DIM * 2); // 10.5MB

  router_kernel<<<dim3(T_TOK / 4), dim3(256), 0, stream>>>(x, gw, idx2, scale2);
  scan_kernel<<<dim3(1), dim3(256), 0, stream>>>(idx2, scale2, ptok, pscale, pairpos, meta);
  gemm1_kernel<<<dim3(H_DIM / 64, MAX_MT), dim3(256), 0, stream>>>(
      x, w1, w3, ptok, pscale, meta, h);
  gemm2_kernel<<<dim3(D_DIM / 64, MAX_MT), dim3(256), 0, stream>>>(h, w2, meta, y);
  combine_kernel<<<dim3(T_TOK / 4), dim3(256), 0, stream>>>(y, pairpos, out);
}